// Round 1
// baseline (1833.727 us; speedup 1.0000x reference)
//
#include <hip/hip_runtime.h>
#include <hip/hip_bf16.h>
#include <math.h>

// Problem constants
#define BATCH 64
#define TSTEP 20
#define FDIM  2048
#define EDIM  512
#define GDIM  1024
#define G3    3072
#define VDIM  32000

// ---------------------------------------------------------------------------
// scales: scale_img[e] = img_g[e]/||img_v[e,:]||, scale_fc[v] = fc_g[v]/||fc_v[v,:]||
// one wave per row. rows = 512 + 32000 = 32512 -> 8128 blocks x 4 waves
// ---------------------------------------------------------------------------
__global__ __launch_bounds__(256) void scales_kernel(
    const float* __restrict__ img_v, const float* __restrict__ img_g,
    const float* __restrict__ fc_v,  const float* __restrict__ fc_g,
    float* __restrict__ scale_img, float* __restrict__ scale_fc)
{
    int wave = blockIdx.x * 4 + (threadIdx.x >> 6);
    int lane = threadIdx.x & 63;
    if (wave < 512) {
        const float* row = img_v + (size_t)wave * FDIM;
        float s = 0.f;
        for (int k = lane; k < FDIM; k += 64) { float v = row[k]; s = fmaf(v, v, s); }
        for (int off = 32; off; off >>= 1) s += __shfl_down(s, off);
        if (lane == 0) scale_img[wave] = img_g[wave] * (1.0f / sqrtf(s));
    } else {
        int r = wave - 512;
        const float* row = fc_v + (size_t)r * GDIM;
        float s = 0.f;
        for (int k = lane; k < GDIM; k += 64) { float v = row[k]; s = fmaf(v, v, s); }
        for (int off = 32; off; off >>= 1) s += __shfl_down(s, off);
        if (lane == 0) scale_fc[r] = fc_g[r] * (1.0f / sqrtf(s));
    }
}

// ---------------------------------------------------------------------------
// img_embed: x_all[0][b][e] = dot(features[b,:], img_v[e,:]) * scale_img[e] + img_b[e]
// one wave per (b,e) output; 64*512 = 32768 waves -> 8192 blocks
// ---------------------------------------------------------------------------
__global__ __launch_bounds__(256) void img_embed_kernel(
    const float* __restrict__ features, const float* __restrict__ img_v,
    const float* __restrict__ scale_img, const float* __restrict__ img_b,
    float* __restrict__ x_all)
{
    int wave = blockIdx.x * 4 + (threadIdx.x >> 6);
    int lane = threadIdx.x & 63;
    int b = wave >> 9;
    int e = wave & 511;
    const float* frow = features + (size_t)b * FDIM;
    const float* vrow = img_v + (size_t)e * FDIM;
    float s = 0.f;
    for (int k = lane; k < FDIM; k += 64) s = fmaf(frow[k], vrow[k], s);
    for (int off = 32; off; off >>= 1) s += __shfl_down(s, off);
    if (lane == 0) x_all[b * EDIM + e] = s * scale_img[e] + img_b[e];
}

// ---------------------------------------------------------------------------
// gather: x_all[t][b][:] = emb_table[input_ids[b][t]] for t = 1..19
// 19*64*512 = 622592 elements -> 2432 blocks x 256
// ---------------------------------------------------------------------------
__global__ __launch_bounds__(256) void gather_kernel(
    const int* __restrict__ ids, const float* __restrict__ emb,
    float* __restrict__ x_all)
{
    int idx = blockIdx.x * 256 + threadIdx.x;
    int e = idx & 511;
    int b = (idx >> 9) & 63;
    int t = (idx >> 15) + 1;
    int id = ids[b * TSTEP + t];
    x_all[(size_t)(t * BATCH + b) * EDIM + e] = emb[(size_t)id * EDIM + e];
}

// ---------------------------------------------------------------------------
// Tiled fp32 GEMM: C = A[M,K] @ B[N,K]^T  (* scale[n]) (+ bias[n])
// BM=BN=64, BK=16, 256 threads, 4x4 microtile per thread.
// Split-K via blockIdx.z (partial k_len chunk; C offset by z*M*N).
// out_mode 0: C[m*N + n]
// out_mode 1: C[(m&63)*(TSTEP*N) + (m>>6)*N + n]   ([B,T,V] permuted store)
// Requires: M % 64 == 0 (or M == 64), N % 64 == 0, k_len % 16 == 0.
// ---------------------------------------------------------------------------
#define BM 64
#define BN 64
#define BK 16

__global__ __launch_bounds__(256) void sgemm_kernel(
    const float* __restrict__ A, const float* __restrict__ Bm,
    float* __restrict__ C, int M, int N, int K, int k_len,
    const float* __restrict__ scale, const float* __restrict__ bias,
    int out_mode)
{
    __shared__ float As[BK][BM + 4];
    __shared__ float Bs[BK][BN + 4];

    const int m0 = blockIdx.y * BM;
    const int n0 = blockIdx.x * BN;
    const int ks = blockIdx.z;
    const int k0 = ks * k_len;
    if (ks > 0) C += (size_t)ks * M * N;

    const int tid = threadIdx.x;
    const int lr = tid >> 2;          // 0..63 row within tile
    const int lk = (tid & 3) << 2;    // 0,4,8,12
    const int tx = tid & 15;
    const int ty = tid >> 4;

    const float* Aload = A + (size_t)(m0 + lr) * K + k0 + lk;
    const float* Bload = Bm + (size_t)(n0 + lr) * K + k0 + lk;

    float acc[4][4];
    #pragma unroll
    for (int i = 0; i < 4; ++i)
        #pragma unroll
        for (int j = 0; j < 4; ++j) acc[i][j] = 0.f;

    for (int kk = 0; kk < k_len; kk += BK) {
        float4 av = *(const float4*)(Aload + kk);
        float4 bv = *(const float4*)(Bload + kk);
        __syncthreads();
        As[lk + 0][lr] = av.x; As[lk + 1][lr] = av.y;
        As[lk + 2][lr] = av.z; As[lk + 3][lr] = av.w;
        Bs[lk + 0][lr] = bv.x; Bs[lk + 1][lr] = bv.y;
        Bs[lk + 2][lr] = bv.z; Bs[lk + 3][lr] = bv.w;
        __syncthreads();
        #pragma unroll
        for (int k = 0; k < BK; ++k) {
            float a[4], b[4];
            #pragma unroll
            for (int i = 0; i < 4; ++i) a[i] = As[k][ty * 4 + i];
            #pragma unroll
            for (int j = 0; j < 4; ++j) b[j] = Bs[k][tx * 4 + j];
            #pragma unroll
            for (int i = 0; i < 4; ++i)
                #pragma unroll
                for (int j = 0; j < 4; ++j)
                    acc[i][j] = fmaf(a[i], b[j], acc[i][j]);
        }
    }

    #pragma unroll
    for (int i = 0; i < 4; ++i) {
        int m = m0 + ty * 4 + i;
        #pragma unroll
        for (int j = 0; j < 4; ++j) {
            int n = n0 + tx * 4 + j;
            float v = acc[i][j];
            if (scale) v *= scale[n];
            if (bias)  v += bias[n];
            if (out_mode == 0) {
                C[(size_t)m * N + n] = v;
            } else {
                C[(size_t)(m & 63) * (TSTEP * N) + (size_t)(m >> 6) * N + n] = v;
            }
        }
    }
}

// ---------------------------------------------------------------------------
// GRU gate elementwise + split-K reduction.
// gh = sum over 8 partials + b_hh; gates from gi_t (b_ih already folded in).
// 64*1024 = 65536 threads -> 256 blocks
// ---------------------------------------------------------------------------
__global__ __launch_bounds__(256) void gru_ew_kernel(
    const float* __restrict__ gi_t,     // [64, 3072]
    const float* __restrict__ gh_part,  // [8][64][3072]
    const float* __restrict__ b_hh,
    const float* __restrict__ h_prev,   // [64, 1024]
    float* __restrict__ h_new)          // [64, 1024]
{
    int idx = blockIdx.x * 256 + threadIdx.x;
    int b = idx >> 10;
    int j = idx & 1023;
    float hr = b_hh[j], hz = b_hh[j + GDIM], hn = b_hh[j + 2 * GDIM];
    #pragma unroll
    for (int s = 0; s < 8; ++s) {
        const float* gp = gh_part + (size_t)s * BATCH * G3 + (size_t)b * G3;
        hr += gp[j]; hz += gp[j + GDIM]; hn += gp[j + 2 * GDIM];
    }
    const float* gi = gi_t + (size_t)b * G3;
    float ir = gi[j], iz = gi[j + GDIM], in_ = gi[j + 2 * GDIM];
    float r = 1.f / (1.f + expf(-(ir + hr)));
    float z = 1.f / (1.f + expf(-(iz + hz)));
    float n = tanhf(in_ + r * hn);
    h_new[idx] = (1.f - z) * n + z * h_prev[idx];
}

// ---------------------------------------------------------------------------
// launch
// ---------------------------------------------------------------------------
extern "C" void kernel_launch(void* const* d_in, const int* in_sizes, int n_in,
                              void* d_out, int out_size, void* d_ws, size_t ws_size,
                              hipStream_t stream)
{
    const float* features = (const float*)d_in[0];
    const int*   ids      = (const int*)  d_in[1];
    const float* emb      = (const float*)d_in[2];
    const float* img_v    = (const float*)d_in[3];
    const float* img_g    = (const float*)d_in[4];
    const float* img_b    = (const float*)d_in[5];
    const float* W_ih     = (const float*)d_in[6];
    const float* W_hh     = (const float*)d_in[7];
    const float* b_ih     = (const float*)d_in[8];
    const float* b_hh     = (const float*)d_in[9];
    const float* fc_v     = (const float*)d_in[10];
    const float* fc_g     = (const float*)d_in[11];
    const float* fc_b     = (const float*)d_in[12];
    float* out = (float*)d_out;
    float* ws  = (float*)d_ws;

    // workspace layout (floats)
    float* scale_img = ws;                       // 512
    float* scale_fc  = ws + 512;                 // 32000
    float* x_all     = ws + 32512;               // 20*64*512   = 655360
    float* gi_all    = ws + 687872;              // 1280*3072   = 3932160
    float* hs_buf    = ws + 4620032;             // 21*64*1024  = 1376256
    float* gh_part   = ws + 5996288;             // 8*64*3072   = 1572864
    // total 7569152 floats = ~30.3 MB

    hipLaunchKernelGGL(scales_kernel, dim3(8128), dim3(256), 0, stream,
                       img_v, img_g, fc_v, fc_g, scale_img, scale_fc);
    hipLaunchKernelGGL(img_embed_kernel, dim3(8192), dim3(256), 0, stream,
                       features, img_v, scale_img, img_b, x_all);
    hipLaunchKernelGGL(gather_kernel, dim3(2432), dim3(256), 0, stream,
                       ids, emb, x_all);
    hipMemsetAsync(hs_buf, 0, (size_t)BATCH * GDIM * sizeof(float), stream);

    // gi_all = x_all @ W_ih^T + b_ih   [1280, 3072]
    hipLaunchKernelGGL(sgemm_kernel, dim3(G3 / BN, (TSTEP * BATCH) / BM, 1), dim3(256), 0, stream,
                       x_all, W_ih, gi_all, TSTEP * BATCH, G3, EDIM, EDIM,
                       (const float*)nullptr, b_ih, 0);

    // GRU recurrence: 20 sequential steps
    for (int t = 0; t < TSTEP; ++t) {
        const float* h_prev = hs_buf + (size_t)t * BATCH * GDIM;
        float* h_new        = hs_buf + (size_t)(t + 1) * BATCH * GDIM;
        // gh partials: [8][64][3072], split-K 8 x 128
        hipLaunchKernelGGL(sgemm_kernel, dim3(G3 / BN, 1, 8), dim3(256), 0, stream,
                           h_prev, W_hh, gh_part, BATCH, G3, GDIM, GDIM / 8,
                           (const float*)nullptr, (const float*)nullptr, 0);
        hipLaunchKernelGGL(gru_ew_kernel, dim3(256), dim3(256), 0, stream,
                           gi_all + (size_t)t * BATCH * G3, gh_part, b_hh, h_prev, h_new);
    }

    // preds[b][t][v] = (hs @ fc_v^T) * scale_fc + fc_b, permuted store to [B,T,V]
    hipLaunchKernelGGL(sgemm_kernel, dim3(VDIM / BN, (TSTEP * BATCH) / BM, 1), dim3(256), 0, stream,
                       hs_buf + (size_t)BATCH * GDIM, fc_v, out, TSTEP * BATCH, VDIM, GDIM, GDIM,
                       scale_fc, fc_b, 1);
}

// Round 2
// 881.071 us; speedup vs baseline: 2.0812x; 2.0812x over previous
//
#include <hip/hip_runtime.h>
#include <hip/hip_bf16.h>
#include <math.h>

// Problem constants
#define BATCH 64
#define TSTEP 20
#define FDIM  2048
#define EDIM  512
#define GDIM  1024
#define G3    3072
#define VDIM  32000

typedef __attribute__((ext_vector_type(8))) short short8x;
typedef __attribute__((ext_vector_type(4))) float f32x4;

static __device__ __forceinline__ unsigned short f2bf(float f) {
    unsigned int u = __float_as_uint(f);
    unsigned int r = (u + 0x7fffu + ((u >> 16) & 1u)) >> 16;
    return (unsigned short)r;
}

// ---------------------------------------------------------------------------
// scale_img[e] = img_g[e]/||img_v[e,:]||  (512 rows, one wave each)
// ---------------------------------------------------------------------------
__global__ __launch_bounds__(256) void scales_img_kernel(
    const float* __restrict__ img_v, const float* __restrict__ img_g,
    float* __restrict__ scale_img)
{
    int wave = blockIdx.x * 4 + (threadIdx.x >> 6);
    int lane = threadIdx.x & 63;
    const float* row = img_v + (size_t)wave * FDIM;
    float s = 0.f;
    for (int k = lane; k < FDIM; k += 64) { float v = row[k]; s = fmaf(v, v, s); }
    for (int off = 32; off; off >>= 1) s += __shfl_down(s, off);
    if (lane == 0) scale_img[wave] = img_g[wave] * (1.0f / sqrtf(s));
}

// ---------------------------------------------------------------------------
// fc row norm + bf16 convert fused: one block per row of fc_v [V,1024]
// ---------------------------------------------------------------------------
__global__ __launch_bounds__(256) void fc_norm_cvt_kernel(
    const float* __restrict__ fc_v, const float* __restrict__ fc_g,
    short* __restrict__ v_bf, float* __restrict__ scale_fc)
{
    int row = blockIdx.x;
    int t = threadIdx.x;
    float4 v = ((const float4*)(fc_v + (size_t)row * GDIM))[t];
    short4 o;
    o.x = (short)f2bf(v.x); o.y = (short)f2bf(v.y);
    o.z = (short)f2bf(v.z); o.w = (short)f2bf(v.w);
    ((short4*)(v_bf + (size_t)row * GDIM))[t] = o;
    float ss = v.x * v.x + v.y * v.y + v.z * v.z + v.w * v.w;
    for (int off = 32; off; off >>= 1) ss += __shfl_down(ss, off);
    __shared__ float red[4];
    if ((t & 63) == 0) red[t >> 6] = ss;
    __syncthreads();
    if (t == 0) {
        float s = red[0] + red[1] + red[2] + red[3];
        scale_fc[row] = fc_g[row] * (1.0f / sqrtf(s));
    }
}

// ---------------------------------------------------------------------------
// generic fp32 -> bf16 convert (n must be divisible by 4)
// ---------------------------------------------------------------------------
__global__ __launch_bounds__(256) void cvt_bf16_kernel(
    const float* __restrict__ in, short* __restrict__ out, int n4)
{
    int i = blockIdx.x * 256 + threadIdx.x;
    if (i >= n4) return;
    float4 v = ((const float4*)in)[i];
    short4 o;
    o.x = (short)f2bf(v.x); o.y = (short)f2bf(v.y);
    o.z = (short)f2bf(v.z); o.w = (short)f2bf(v.w);
    ((short4*)out)[i] = o;
}

// ---------------------------------------------------------------------------
// img_embed: x_all[0][b][e] = dot(features[b,:], img_v[e,:]) * scale_img[e] + img_b[e]
// ---------------------------------------------------------------------------
__global__ __launch_bounds__(256) void img_embed_kernel(
    const float* __restrict__ features, const float* __restrict__ img_v,
    const float* __restrict__ scale_img, const float* __restrict__ img_b,
    float* __restrict__ x_all)
{
    int wave = blockIdx.x * 4 + (threadIdx.x >> 6);
    int lane = threadIdx.x & 63;
    int b = wave >> 9;
    int e = wave & 511;
    const float* frow = features + (size_t)b * FDIM;
    const float* vrow = img_v + (size_t)e * FDIM;
    float s = 0.f;
    for (int k = lane; k < FDIM; k += 64) s = fmaf(frow[k], vrow[k], s);
    for (int off = 32; off; off >>= 1) s += __shfl_down(s, off);
    if (lane == 0) x_all[b * EDIM + e] = s * scale_img[e] + img_b[e];
}

// ---------------------------------------------------------------------------
// gather: x_all[t][b][:] = emb_table[input_ids[b][t]] for t = 1..19
// ---------------------------------------------------------------------------
__global__ __launch_bounds__(256) void gather_kernel(
    const int* __restrict__ ids, const float* __restrict__ emb,
    float* __restrict__ x_all)
{
    int idx = blockIdx.x * 256 + threadIdx.x;
    int e = idx & 511;
    int b = (idx >> 9) & 63;
    int t = (idx >> 15) + 1;
    int id = ids[b * TSTEP + t];
    x_all[(size_t)(t * BATCH + b) * EDIM + e] = emb[(size_t)id * EDIM + e];
}

// ---------------------------------------------------------------------------
// bf16 MFMA GEMM: C[M,N] = A[M,K](bf16) @ B[N,K](bf16)^T (*scale[n]) (+bias[n])
// 128x128 tile, BK=32, 256 threads = 4 waves in 2x2 arrangement, each wave
// 64x64 via 4x4 grid of 16x16x32 MFMAs. global_load_lds width-16 staging with
// XOR-swizzled LDS chunks (c ^ ((row>>1)&3)) for conflict-free ds_read_b128.
// Requires M%128==0, N%128==0, K%32==0. out_mode 1 = [B,T,V] permuted store.
// ---------------------------------------------------------------------------
__global__ __launch_bounds__(256) void mfma_gemm_kernel(
    const short* __restrict__ A, const short* __restrict__ B,
    float* __restrict__ C, int M, int N, int K,
    const float* __restrict__ scale, const float* __restrict__ bias,
    int out_mode)
{
    __shared__ short As[128 * 32];
    __shared__ short Bs[128 * 32];

    const int tid  = threadIdx.x;
    const int wave = tid >> 6;
    const int lane = tid & 63;
    const int m0 = blockIdx.y * 128;
    const int n0 = blockIdx.x * 128;

    // staging: lane covers 16B chunk; row-in-16 = lane>>2, swizzled source chunk
    const int srow   = lane >> 2;                       // 0..15
    const int schunk = (lane & 3) ^ ((lane >> 3) & 3);  // swizzle key s(r)=(r>>1)&3

    // fragment addressing
    const int wm = wave >> 1, wn = wave & 1;
    const int fr = lane & 15;          // row within 16-tile (operand row)
    const int q  = lane >> 4;          // quad -> k-chunk
    const int kchunk = (q ^ ((fr >> 1) & 3)) * 8;       // element offset of 16B chunk

    f32x4 acc[4][4];
    #pragma unroll
    for (int i = 0; i < 4; ++i)
        #pragma unroll
        for (int j = 0; j < 4; ++j)
            acc[i][j] = (f32x4)(0.f);

    for (int k0 = 0; k0 < K; k0 += 32) {
        __syncthreads();   // previous iter's LDS reads complete
        #pragma unroll
        for (int p = 0; p < 2; ++p) {
            int mi = wave * 2 + p;                 // 16-row group 0..7
            int rA = mi * 16 + srow;
            const short* gA = A + (size_t)(m0 + rA) * K + k0 + schunk * 8;
            const short* gB = B + (size_t)(n0 + rA) * K + k0 + schunk * 8;
            __builtin_amdgcn_global_load_lds(
                (const __attribute__((address_space(1))) void*)gA,
                (__attribute__((address_space(3))) void*)(As + mi * 512), 16, 0, 0);
            __builtin_amdgcn_global_load_lds(
                (const __attribute__((address_space(1))) void*)gB,
                (__attribute__((address_space(3))) void*)(Bs + mi * 512), 16, 0, 0);
        }
        __syncthreads();   // compiler drains vmcnt before s_barrier -> staging visible

        short8x a[4], b[4];
        #pragma unroll
        for (int i = 0; i < 4; ++i)
            a[i] = *(const short8x*)(As + (wm * 64 + i * 16 + fr) * 32 + kchunk);
        #pragma unroll
        for (int j = 0; j < 4; ++j)
            b[j] = *(const short8x*)(Bs + (wn * 64 + j * 16 + fr) * 32 + kchunk);
        #pragma unroll
        for (int i = 0; i < 4; ++i)
            #pragma unroll
            for (int j = 0; j < 4; ++j)
                acc[i][j] = __builtin_amdgcn_mfma_f32_16x16x32_bf16(a[i], b[j], acc[i][j], 0, 0, 0);
    }

    // epilogue: D mapping col=lane&15, row=(lane>>4)*4+reg
    #pragma unroll
    for (int i = 0; i < 4; ++i) {
        #pragma unroll
        for (int r = 0; r < 4; ++r) {
            int m = m0 + wm * 64 + i * 16 + q * 4 + r;
            #pragma unroll
            for (int j = 0; j < 4; ++j) {
                int n = n0 + wn * 64 + j * 16 + fr;
                float v = acc[i][j][r];
                if (scale) v *= scale[n];
                if (bias)  v += bias[n];
                if (out_mode == 0) {
                    C[(size_t)m * N + n] = v;
                } else {
                    C[(size_t)(m & 63) * (TSTEP * N) + (size_t)(m >> 6) * N + n] = v;
                }
            }
        }
    }
}

// ---------------------------------------------------------------------------
// fp32 tiled GEMM (kept for the small sequential GRU W_hh matmuls)
// ---------------------------------------------------------------------------
#define BM 64
#define BN 64
#define BK 16

__global__ __launch_bounds__(256) void sgemm_kernel(
    const float* __restrict__ A, const float* __restrict__ Bm,
    float* __restrict__ C, int M, int N, int K, int k_len)
{
    __shared__ float As[BK][BM + 4];
    __shared__ float Bs[BK][BN + 4];

    const int m0 = blockIdx.y * BM;
    const int n0 = blockIdx.x * BN;
    const int ks = blockIdx.z;
    const int k0 = ks * k_len;
    if (ks > 0) C += (size_t)ks * M * N;

    const int tid = threadIdx.x;
    const int lr = tid >> 2;
    const int lk = (tid & 3) << 2;
    const int tx = tid & 15;
    const int ty = tid >> 4;

    const float* Aload = A + (size_t)(m0 + lr) * K + k0 + lk;
    const float* Bload = Bm + (size_t)(n0 + lr) * K + k0 + lk;

    float acc[4][4];
    #pragma unroll
    for (int i = 0; i < 4; ++i)
        #pragma unroll
        for (int j = 0; j < 4; ++j) acc[i][j] = 0.f;

    for (int kk = 0; kk < k_len; kk += BK) {
        float4 av = *(const float4*)(Aload + kk);
        float4 bv = *(const float4*)(Bload + kk);
        __syncthreads();
        As[lk + 0][lr] = av.x; As[lk + 1][lr] = av.y;
        As[lk + 2][lr] = av.z; As[lk + 3][lr] = av.w;
        Bs[lk + 0][lr] = bv.x; Bs[lk + 1][lr] = bv.y;
        Bs[lk + 2][lr] = bv.z; Bs[lk + 3][lr] = bv.w;
        __syncthreads();
        #pragma unroll
        for (int k = 0; k < BK; ++k) {
            float a[4], b[4];
            #pragma unroll
            for (int i = 0; i < 4; ++i) a[i] = As[k][ty * 4 + i];
            #pragma unroll
            for (int j = 0; j < 4; ++j) b[j] = Bs[k][tx * 4 + j];
            #pragma unroll
            for (int i = 0; i < 4; ++i)
                #pragma unroll
                for (int j = 0; j < 4; ++j)
                    acc[i][j] = fmaf(a[i], b[j], acc[i][j]);
        }
    }

    #pragma unroll
    for (int i = 0; i < 4; ++i) {
        int m = m0 + ty * 4 + i;
        #pragma unroll
        for (int j = 0; j < 4; ++j) {
            int n = n0 + tx * 4 + j;
            C[(size_t)m * N + n] = acc[i][j];
        }
    }
}

// ---------------------------------------------------------------------------
// GRU gate elementwise + split-K reduction
// ---------------------------------------------------------------------------
__global__ __launch_bounds__(256) void gru_ew_kernel(
    const float* __restrict__ gi_t, const float* __restrict__ gh_part,
    const float* __restrict__ b_hh, const float* __restrict__ h_prev,
    float* __restrict__ h_new)
{
    int idx = blockIdx.x * 256 + threadIdx.x;
    int b = idx >> 10;
    int j = idx & 1023;
    float hr = b_hh[j], hz = b_hh[j + GDIM], hn = b_hh[j + 2 * GDIM];
    #pragma unroll
    for (int s = 0; s < 8; ++s) {
        const float* gp = gh_part + (size_t)s * BATCH * G3 + (size_t)b * G3;
        hr += gp[j]; hz += gp[j + GDIM]; hn += gp[j + 2 * GDIM];
    }
    const float* gi = gi_t + (size_t)b * G3;
    float ir = gi[j], iz = gi[j + GDIM], in_ = gi[j + 2 * GDIM];
    float r = 1.f / (1.f + expf(-(ir + hr)));
    float z = 1.f / (1.f + expf(-(iz + hz)));
    float n = tanhf(in_ + r * hn);
    h_new[idx] = (1.f - z) * n + z * h_prev[idx];
}

// ---------------------------------------------------------------------------
// launch
// ---------------------------------------------------------------------------
extern "C" void kernel_launch(void* const* d_in, const int* in_sizes, int n_in,
                              void* d_out, int out_size, void* d_ws, size_t ws_size,
                              hipStream_t stream)
{
    const float* features = (const float*)d_in[0];
    const int*   ids      = (const int*)  d_in[1];
    const float* emb      = (const float*)d_in[2];
    const float* img_v    = (const float*)d_in[3];
    const float* img_g    = (const float*)d_in[4];
    const float* img_b    = (const float*)d_in[5];
    const float* W_ih     = (const float*)d_in[6];
    const float* W_hh     = (const float*)d_in[7];
    const float* b_ih     = (const float*)d_in[8];
    const float* b_hh     = (const float*)d_in[9];
    const float* fc_v     = (const float*)d_in[10];
    const float* fc_g     = (const float*)d_in[11];
    const float* fc_b     = (const float*)d_in[12];
    float* out = (float*)d_out;
    float* ws  = (float*)d_ws;

    // workspace layout (float offsets); fcv_bf overlays the dead phase-A region
    float* scale_img = ws;                          //      512
    float* scale_fc  = ws + 512;                    //    32000
    float* hs_buf    = ws + 32512;                  //  1376256  [21][64][1024]
    short* hs_bf     = (short*)(ws + 1408768);      //  1310720 shorts (655360 f)
    // phase-A region @ 2064128 (dead before fcv_bf conversion):
    float* x_all     = ws + 2064128;                //   655360  [20][64][512]
    short* x_bf      = (short*)(ws + 2719488);      //   655360 shorts
    short* wih_bf    = (short*)(ws + 3047168);      //  1572864 shorts
    float* gi_all    = ws + 3833600;                //  3932160  [1280][3072]
    float* gh_part   = ws + 7765760;                //  1572864  [8][64][3072]
    short* fcv_bf    = (short*)(ws + 2064128);      // 32768000 shorts (overlay)
    // peak usage: 18448128 floats = ~70.4 MiB

    hipLaunchKernelGGL(scales_img_kernel, dim3(128), dim3(256), 0, stream,
                       img_v, img_g, scale_img);
    hipLaunchKernelGGL(img_embed_kernel, dim3(8192), dim3(256), 0, stream,
                       features, img_v, scale_img, img_b, x_all);
    hipLaunchKernelGGL(gather_kernel, dim3(2432), dim3(256), 0, stream,
                       ids, emb, x_all);
    hipLaunchKernelGGL(cvt_bf16_kernel, dim3((TSTEP * BATCH * EDIM / 4 + 255) / 256), dim3(256), 0, stream,
                       x_all, x_bf, TSTEP * BATCH * EDIM / 4);
    hipLaunchKernelGGL(cvt_bf16_kernel, dim3((G3 * EDIM / 4 + 255) / 256), dim3(256), 0, stream,
                       W_ih, wih_bf, G3 * EDIM / 4);
    hipMemsetAsync(hs_buf, 0, (size_t)BATCH * GDIM * sizeof(float), stream);

    // gi_all = x_bf @ wih_bf^T + b_ih   [1280, 3072], bf16 MFMA
    hipLaunchKernelGGL(mfma_gemm_kernel, dim3(G3 / 128, (TSTEP * BATCH) / 128, 1), dim3(256), 0, stream,
                       x_bf, wih_bf, gi_all, TSTEP * BATCH, G3, EDIM,
                       (const float*)nullptr, b_ih, 0);

    // GRU recurrence: 20 sequential steps (fp32 for accuracy)
    for (int t = 0; t < TSTEP; ++t) {
        const float* h_prev = hs_buf + (size_t)t * BATCH * GDIM;
        float* h_new        = hs_buf + (size_t)(t + 1) * BATCH * GDIM;
        hipLaunchKernelGGL(sgemm_kernel, dim3(G3 / BN, 1, 8), dim3(256), 0, stream,
                           h_prev, W_hh, gh_part, BATCH, G3, GDIM, GDIM / 8);
        hipLaunchKernelGGL(gru_ew_kernel, dim3(256), dim3(256), 0, stream,
                           gi_all + (size_t)t * BATCH * G3, gh_part, b_hh, h_prev, h_new);
    }

    // hs -> bf16 (rows 1..20 of hs_buf)
    hipLaunchKernelGGL(cvt_bf16_kernel, dim3((TSTEP * BATCH * GDIM / 4 + 255) / 256), dim3(256), 0, stream,
                       hs_buf + (size_t)BATCH * GDIM, hs_bf, TSTEP * BATCH * GDIM / 4);
    // fc_v norms + bf16 convert (after GRU: fcv_bf overlays dead gi/gh region)
    hipLaunchKernelGGL(fc_norm_cvt_kernel, dim3(VDIM), dim3(256), 0, stream,
                       fc_v, fc_g, fcv_bf, scale_fc);

    // preds = (hs_bf @ fcv_bf^T) * scale_fc + fc_b, permuted [B,T,V] store
    hipLaunchKernelGGL(mfma_gemm_kernel, dim3(VDIM / 128, (TSTEP * BATCH) / 128, 1), dim3(256), 0, stream,
                       hs_bf, fcv_bf, out, TSTEP * BATCH, VDIM, GDIM,
                       scale_fc, fc_b, 1);
}